// Round 23
// baseline (236.336 us; speedup 1.0000x reference)
//
#include <hip/hip_runtime.h>

typedef unsigned short ushort_t;
typedef __attribute__((ext_vector_type(8))) short short8;
typedef __attribute__((ext_vector_type(4))) float f32x4;

#define AS1(p) ((const __attribute__((address_space(1))) void*)(p))
#define AS3(p) ((__attribute__((address_space(3))) void*)(p))

__device__ __forceinline__ ushort_t f2bf(float f){
  unsigned u = __float_as_uint(f);
  u += 0x7FFFu + ((u>>16)&1u);
  return (ushort_t)(u>>16);
}
__device__ __forceinline__ float bf2f(ushort_t h){
  return __uint_as_float(((unsigned)h)<<16);
}

// ---------------------------------------------------------------- conv fp32->bf16
__global__ __launch_bounds__(256) void conv_f2b(const float* __restrict__ src,
                                                ushort_t* __restrict__ dst, int n){
  int i = (blockIdx.x*256 + threadIdx.x)*4;
  if (i < n){
    float4 v = *(const float4*)&src[i];
    ushort_t o0=f2bf(v.x), o1=f2bf(v.y), o2=f2bf(v.z), o3=f2bf(v.w);
    ushort4 o; o.x=o0; o.y=o1; o.z=o2; o.w=o3;
    *(ushort4*)&dst[i] = o;
  }
}

// ---------------------------------------------------------------- LoRA h = X @ A0^T * (da*db)  (f32 input, fused bf16 conv)
__global__ __launch_bounds__(256) void lora_h_f32(const float* __restrict__ X,
                                                  ushort_t* __restrict__ Xbf,
                                                  const float* __restrict__ A0,
                                                  const float* __restrict__ da,
                                                  const float* __restrict__ db,
                                                  float* __restrict__ out, int K){
  int m = blockIdx.x;
  int tid = threadIdx.x, lane = tid & 63, w = tid >> 6;
  float part[8] = {0,0,0,0,0,0,0,0};
  for (int k = tid; k < K; k += 256){
    float xv = X[(size_t)m*K + k];
    Xbf[(size_t)m*K + k] = f2bf(xv);
    #pragma unroll
    for (int r=0;r<8;++r) part[r] += xv * A0[r*K + k];
  }
  #pragma unroll
  for (int r=0;r<8;++r)
    for (int d=1;d<64;d<<=1) part[r] += __shfl_xor(part[r], d, 64);
  __shared__ float wsum[4][8];
  if (lane==0){
    #pragma unroll
    for (int r=0;r<8;++r) wsum[w][r] = part[r];
  }
  __syncthreads();
  if (tid < 8){
    float s = wsum[0][tid]+wsum[1][tid]+wsum[2][tid]+wsum[3][tid];
    out[(size_t)m*8 + tid] = s * da[tid]*db[tid];
  }
}

// ---------------------------------------------------------------- reduce h_part over heads
__global__ __launch_bounds__(256) void lora_reduce(const float* __restrict__ hpart,
                                                   const float* __restrict__ da,
                                                   const float* __restrict__ db,
                                                   float* __restrict__ out){
  int i = blockIdx.x*256 + threadIdx.x;   // 0..32767 (4096 rows x 8 ranks)
  int r = i & 7;
  float s = 0.f;
  #pragma unroll
  for (int hh=0; hh<16; ++hh) s += hpart[(size_t)hh*32768 + i];
  out[i] = s * da[r]*db[r];
}

// ---------------------------------------------------------------- 256x192 3-phase GEMM + LoRA (bf16 out, QKV)
__global__ __launch_bounds__(512, 1) void gemm256x192_lora(
    const ushort_t* __restrict__ A, const ushort_t* __restrict__ Bw,
    const float* __restrict__ hmat, const float* __restrict__ B0,
    ushort_t* __restrict__ C, int M, int N, int K)
{
  __shared__ __align__(16) char smem[114688];
  const int tid = threadIdx.x, lane = tid & 63, w = tid >> 6;
  const int wm = w >> 1, wn = w & 1;

  const int nbn = N / 192;
  const int nwg = (M >> 8) * nbn;
  const int q8 = nwg >> 3;
  const int swz = ((int)blockIdx.x & 7)*q8 + ((int)blockIdx.x >> 3);
  const int m0 = (swz / nbn) << 8, n0 = (swz % nbn) * 192;

  const int NTt = K >> 6;
  const int srow8  = tid >> 3;
  const int schunk = (lane & 7) ^ (lane >> 3);

  #define STAGE_AU(u, tt, bb) do { \
    const ushort_t* g_ = A + (size_t)(m0 + (u)*64 + srow8)*K + (tt)*64 + schunk*8; \
    __builtin_amdgcn_global_load_lds(AS1(g_), AS3(smem + (bb)*32768 + (u)*8192 + tid*16), 16, 0, 0); \
  } while(0)
  #define STAGE_BU(u, tt, bb) do { \
    const ushort_t* g_ = Bw + (size_t)(n0 + (u)*64 + srow8)*K + (tt)*64 + schunk*8; \
    __builtin_amdgcn_global_load_lds(AS1(g_), AS3(smem + 65536 + (bb)*24576 + (u)*8192 + tid*16), 16, 0, 0); \
  } while(0)

  #define RDA(bb, q, kk) (*(const short8*)(smem + (bb)*32768 + \
      ((q)*64 + wm*16 + (lane&15))*128 + ((((kk)*4 + (lane>>4)) ^ (lane&7))<<4)))
  #define RDB(bb, r, kk) (*(const short8*)(smem + 65536 + (bb)*24576 + \
      ((r)*32 + wn*16 + (lane&15))*128 + ((((kk)*4 + (lane>>4)) ^ (lane&7))<<4)))

  #define MM(q, r, bi) do{ \
    acc[q][r] = __builtin_amdgcn_mfma_f32_16x16x32_bf16(aF[q][0], bF[bi][0], acc[q][r], 0,0,0); \
    acc[q][r] = __builtin_amdgcn_mfma_f32_16x16x32_bf16(aF[q][1], bF[bi][1], acc[q][r], 0,0,0); \
  }while(0)

  #define BARRIER() asm volatile("s_barrier" ::: "memory")

  short8 aF[4][2];
  short8 bF[2][2];
  f32x4 acc[4][6] = {};

  STAGE_AU(0,0,0); STAGE_AU(1,0,0); STAGE_AU(2,0,0); STAGE_AU(3,0,0);
  STAGE_BU(0,0,0); STAGE_BU(1,0,0); STAGE_BU(2,0,0);
  asm volatile("s_waitcnt vmcnt(2)" ::: "memory");
  BARRIER();

  for (int t = 0; t < NTt-1; ++t){
    const int b = t & 1, nb = b ^ 1;
    #pragma unroll
    for (int q=0;q<4;++q){ aF[q][0]=RDA(b,q,0); aF[q][1]=RDA(b,q,1); }
    #pragma unroll
    for (int rl=0;rl<2;++rl){ bF[rl][0]=RDB(b,rl,0); bF[rl][1]=RDB(b,rl,1); }
    STAGE_AU(0,t+1,nb); STAGE_AU(1,t+1,nb);
    __builtin_amdgcn_s_setprio(1);
    MM(0,0,0); MM(0,1,1); MM(1,0,0); MM(1,1,1);
    MM(2,0,0); MM(2,1,1); MM(3,0,0); MM(3,1,1);
    __builtin_amdgcn_s_setprio(0);
    asm volatile("s_waitcnt vmcnt(3)" ::: "memory");
    BARRIER();
    #pragma unroll
    for (int rl=0;rl<2;++rl){ bF[rl][0]=RDB(b,rl+2,0); bF[rl][1]=RDB(b,rl+2,1); }
    STAGE_AU(2,t+1,nb); STAGE_AU(3,t+1,nb); STAGE_BU(0,t+1,nb);
    __builtin_amdgcn_s_setprio(1);
    MM(0,2,0); MM(0,3,1); MM(1,2,0); MM(1,3,1);
    MM(2,2,0); MM(2,3,1); MM(3,2,0); MM(3,3,1);
    __builtin_amdgcn_s_setprio(0);
    asm volatile("s_waitcnt vmcnt(5)" ::: "memory");
    BARRIER();
    #pragma unroll
    for (int rl=0;rl<2;++rl){ bF[rl][0]=RDB(b,rl+4,0); bF[rl][1]=RDB(b,rl+4,1); }
    STAGE_BU(1,t+1,nb); STAGE_BU(2,t+1,nb);
    __builtin_amdgcn_s_setprio(1);
    MM(0,4,0); MM(0,5,1); MM(1,4,0); MM(1,5,1);
    MM(2,4,0); MM(2,5,1); MM(3,4,0); MM(3,5,1);
    __builtin_amdgcn_s_setprio(0);
    asm volatile("s_waitcnt lgkmcnt(0)" ::: "memory");
    asm volatile("s_waitcnt vmcnt(2)" ::: "memory");
    BARRIER();
  }

  {
    const int b = (NTt-1) & 1;
    #pragma unroll
    for (int q=0;q<4;++q){ aF[q][0]=RDA(b,q,0); aF[q][1]=RDA(b,q,1); }
    #pragma unroll
    for (int rl=0;rl<2;++rl){ bF[rl][0]=RDB(b,rl,0); bF[rl][1]=RDB(b,rl,1); }
    __builtin_amdgcn_s_setprio(1);
    MM(0,0,0); MM(0,1,1); MM(1,0,0); MM(1,1,1);
    MM(2,0,0); MM(2,1,1); MM(3,0,0); MM(3,1,1);
    __builtin_amdgcn_s_setprio(0);
    asm volatile("s_waitcnt vmcnt(1)" ::: "memory");
    BARRIER();
    #pragma unroll
    for (int rl=0;rl<2;++rl){ bF[rl][0]=RDB(b,rl+2,0); bF[rl][1]=RDB(b,rl+2,1); }
    __builtin_amdgcn_s_setprio(1);
    MM(0,2,0); MM(0,3,1); MM(1,2,0); MM(1,3,1);
    MM(2,2,0); MM(2,3,1); MM(3,2,0); MM(3,3,1);
    __builtin_amdgcn_s_setprio(0);
    asm volatile("s_waitcnt vmcnt(0)" ::: "memory");
    BARRIER();
    #pragma unroll
    for (int rl=0;rl<2;++rl){ bF[rl][0]=RDB(b,rl+4,0); bF[rl][1]=RDB(b,rl+4,1); }
    MM(0,4,0); MM(0,5,1); MM(1,4,0); MM(1,5,1);
    MM(2,4,0); MM(2,5,1); MM(3,4,0); MM(3,5,1);
  }

  float b0v[6][8];
  #pragma unroll
  for (int r=0;r<6;++r){
    int col = n0 + r*32 + wn*16 + (lane&15);
    const float4* bp = (const float4*)&B0[(size_t)col*8];
    float4 u0 = bp[0], u1 = bp[1];
    b0v[r][0]=u0.x; b0v[r][1]=u0.y; b0v[r][2]=u0.z; b0v[r][3]=u0.w;
    b0v[r][4]=u1.x; b0v[r][5]=u1.y; b0v[r][6]=u1.z; b0v[r][7]=u1.w;
  }
  #pragma unroll
  for (int q=0;q<4;++q){
    #pragma unroll
    for (int jj=0;jj<4;++jj){
      int row = m0 + q*64 + wm*16 + (lane>>4)*4 + jj;
      const float4* hp = (const float4*)&hmat[(size_t)row*8];
      float4 h0 = hp[0], h1 = hp[1];
      #pragma unroll
      for (int r=0;r<6;++r){
        float lor = h0.x*b0v[r][0]+h0.y*b0v[r][1]+h0.z*b0v[r][2]+h0.w*b0v[r][3]
                  + h1.x*b0v[r][4]+h1.y*b0v[r][5]+h1.z*b0v[r][6]+h1.w*b0v[r][7];
        int col = n0 + r*32 + wn*16 + (lane&15);
        C[(size_t)row*N + col] = f2bf(acc[q][r][jj] + 0.125f*lor);
      }
    }
  }
  #undef STAGE_AU
  #undef STAGE_BU
  #undef RDA
  #undef RDB
  #undef MM
  #undef BARRIER
}

// ---------------------------------------------------------------- 128x256 2-phase GEMM + LoRA (out-proj)
template<int MODE>
__global__ __launch_bounds__(512, 1) void gemm128x256_lora(
    const ushort_t* __restrict__ A, const ushort_t* __restrict__ Bw,
    const float* __restrict__ hmat, const float* __restrict__ B0,
    void* __restrict__ C, int M, int N, int K)
{
  __shared__ __align__(16) char smem[98304];
  const int tid = threadIdx.x, lane = tid & 63, w = tid >> 6;
  const int wm = w >> 2, wn = w & 3;

  const int nbn = N >> 8;
  const int nwg = (M >> 7) * nbn;
  const int q8 = nwg >> 3;
  const int swz = ((int)blockIdx.x & 7)*q8 + ((int)blockIdx.x >> 3);
  const int m0 = (swz / nbn) << 7, n0 = (swz % nbn) << 8;

  const int NTt = K >> 6;

  const int srow8  = tid >> 3;
  const int schunk = (lane & 7) ^ (lane >> 3);

  #define STAGE_AU(u, tt, bb) do { \
    const ushort_t* g_ = A + (size_t)(m0 + (u)*64 + srow8)*K + (tt)*64 + schunk*8; \
    __builtin_amdgcn_global_load_lds(AS1(g_), AS3(smem + (bb)*16384 + (u)*8192 + w*1024), 16, 0, 0); \
  } while(0)
  #define STAGE_BU(u, tt, bb) do { \
    const ushort_t* g_ = Bw + (size_t)(n0 + (u)*64 + srow8)*K + (tt)*64 + schunk*8; \
    __builtin_amdgcn_global_load_lds(AS1(g_), AS3(smem + 32768 + (bb)*32768 + (u)*8192 + w*1024), 16, 0, 0); \
  } while(0)

  #define RDA(bb, q, kk) (*(const short8*)(smem + (bb)*16384 + \
      ((q)*32 + wm*16 + (lane&15))*128 + ((((kk)*4 + (lane>>4)) ^ (lane&7))<<4)))
  #define RDB(bb, rg, kk) (*(const short8*)(smem + 32768 + (bb)*32768 + \
      ((rg)*64 + wn*16 + (lane&15))*128 + ((((kk)*4 + (lane>>4)) ^ (lane&7))<<4)))

  #define MM0(q,rl) do{ \
    acc[q][rl] = __builtin_amdgcn_mfma_f32_16x16x32_bf16(aF[q][0], bF[rl][0], acc[q][rl], 0,0,0); \
    acc[q][rl] = __builtin_amdgcn_mfma_f32_16x16x32_bf16(aF[q][1], bF[rl][1], acc[q][rl], 0,0,0); \
  }while(0)
  #define MM1(q,rl) do{ \
    acc[q][(rl)+2] = __builtin_amdgcn_mfma_f32_16x16x32_bf16(aF[q][0], bF[rl][0], acc[q][(rl)+2], 0,0,0); \
    acc[q][(rl)+2] = __builtin_amdgcn_mfma_f32_16x16x32_bf16(aF[q][1], bF[rl][1], acc[q][(rl)+2], 0,0,0); \
  }while(0)

  #define BARRIER() asm volatile("s_barrier" ::: "memory")

  short8 aF[4][2];
  short8 bF[2][2];
  f32x4 acc[4][4] = {};

  STAGE_AU(0,0,0); STAGE_AU(1,0,0); STAGE_BU(0,0,0); STAGE_BU(1,0,0);
  STAGE_BU(2,0,0); STAGE_BU(3,0,0);
  asm volatile("s_waitcnt vmcnt(2)" ::: "memory");
  BARRIER();

  for (int t = 0; t < NTt-1; ++t){
    const int b = t & 1, nb = b ^ 1;
    #pragma unroll
    for (int q=0;q<4;++q){ aF[q][0]=RDA(b,q,0); aF[q][1]=RDA(b,q,1); }
    #pragma unroll
    for (int rl=0;rl<2;++rl){ bF[rl][0]=RDB(b,rl,0); bF[rl][1]=RDB(b,rl,1); }
    STAGE_AU(0,t+1,nb); STAGE_AU(1,t+1,nb); STAGE_BU(0,t+1,nb); STAGE_BU(1,t+1,nb);
    __builtin_amdgcn_s_setprio(1);
    MM0(0,0); MM0(0,1); MM0(1,0); MM0(1,1);
    MM0(2,0); MM0(2,1); MM0(3,0); MM0(3,1);
    __builtin_amdgcn_s_setprio(0);
    asm volatile("s_waitcnt vmcnt(4)" ::: "memory");
    BARRIER();
    #pragma unroll
    for (int rl=0;rl<2;++rl){ bF[rl][0]=RDB(b,rl+2,0); bF[rl][1]=RDB(b,rl+2,1); }
    STAGE_BU(2,t+1,nb); STAGE_BU(3,t+1,nb);
    __builtin_amdgcn_s_setprio(1);
    MM1(0,0); MM1(0,1); MM1(1,0); MM1(1,1);
    MM1(2,0); MM1(2,1); MM1(3,0); MM1(3,1);
    __builtin_amdgcn_s_setprio(0);
    asm volatile("s_waitcnt lgkmcnt(0)" ::: "memory");
    asm volatile("s_waitcnt vmcnt(2)" ::: "memory");
    BARRIER();
  }

  {
    const int b = (NTt-1) & 1;
    #pragma unroll
    for (int q=0;q<4;++q){ aF[q][0]=RDA(b,q,0); aF[q][1]=RDA(b,q,1); }
    #pragma unroll
    for (int rl=0;rl<2;++rl){ bF[rl][0]=RDB(b,rl,0); bF[rl][1]=RDB(b,rl,1); }
    __builtin_amdgcn_s_setprio(1);
    MM0(0,0); MM0(0,1); MM0(1,0); MM0(1,1);
    MM0(2,0); MM0(2,1); MM0(3,0); MM0(3,1);
    __builtin_amdgcn_s_setprio(0);
    asm volatile("s_waitcnt vmcnt(0)" ::: "memory");
    BARRIER();
    #pragma unroll
    for (int rl=0;rl<2;++rl){ bF[rl][0]=RDB(b,rl+2,0); bF[rl][1]=RDB(b,rl+2,1); }
    MM1(0,0); MM1(0,1); MM1(1,0); MM1(1,1);
    MM1(2,0); MM1(2,1); MM1(3,0); MM1(3,1);
  }

  float b0v[4][8];
  #pragma unroll
  for (int r=0;r<4;++r){
    int col = n0 + r*64 + wn*16 + (lane&15);
    const float4* bp = (const float4*)&B0[(size_t)col*8];
    float4 u0 = bp[0], u1 = bp[1];
    b0v[r][0]=u0.x; b0v[r][1]=u0.y; b0v[r][2]=u0.z; b0v[r][3]=u0.w;
    b0v[r][4]=u1.x; b0v[r][5]=u1.y; b0v[r][6]=u1.z; b0v[r][7]=u1.w;
  }
  #pragma unroll
  for (int q=0;q<4;++q){
    #pragma unroll
    for (int jj=0;jj<4;++jj){
      int row = m0 + q*32 + wm*16 + (lane>>4)*4 + jj;
      const float4* hp = (const float4*)&hmat[(size_t)row*8];
      float4 h0 = hp[0], h1 = hp[1];
      #pragma unroll
      for (int r=0;r<4;++r){
        float lor = h0.x*b0v[r][0]+h0.y*b0v[r][1]+h0.z*b0v[r][2]+h0.w*b0v[r][3]
                  + h1.x*b0v[r][4]+h1.y*b0v[r][5]+h1.z*b0v[r][6]+h1.w*b0v[r][7];
        int col = n0 + r*64 + wn*16 + (lane&15);
        float v = acc[q][r][jj] + 0.125f*lor;
        if (MODE==0) ((ushort_t*)C)[(size_t)row*N + col] = f2bf(v);
        else         ((float*)C)[(size_t)row*N + col]    = v;
      }
    }
  }
  #undef STAGE_AU
  #undef STAGE_BU
  #undef RDA
  #undef RDB
  #undef MM0
  #undef MM1
  #undef BARRIER
}

// ---------------------------------------------------------------- RoPE (in place on qkv bf16)
__global__ __launch_bounds__(256) void rope_kernel(ushort_t* __restrict__ qkv,
                                                   const float* __restrict__ cosb,
                                                   const float* __restrict__ sinb){
  int idx = blockIdx.x*256 + threadIdx.x;
  int d = idx & 7;
  int g = idx >> 3;
  int h_ = g & 15;
  int s  = (g>>4) & 1;
  int t  = (g>>5) & 511;
  int b  = g >> 14;
  size_t base = (size_t)(b*512 + t)*6144 + s*2048 + h_*128;
  float x1 = bf2f(qkv[base+d]), x2 = bf2f(qkv[base+d+8]);
  float c = cosb[t*8+d], sn = sinb[t*8+d];
  qkv[base+d]   = f2bf(x1*c - x2*sn);
  qkv[base+d+8] = f2bf(x2*c + x1*sn);
}

// ---------------------------------------------------------------- flash attention (+ fused h_out partials)
// QBLK=64 (4 waves x 16 rows), KVBLK=64, single-buffered, 4 blocks/CU (40KB LDS).
// Balanced qt remap: qtab co-resident sets {0,7,3,4}/{1,6,2,5} -> exactly 18 tile-units/CU.
// T13 defer-max. Epilogue: y (bf16) + h_part[hh][row][8].
__global__ __launch_bounds__(256) void attn_kernel(const ushort_t* __restrict__ qkv,
                                                   ushort_t* __restrict__ y,
                                                   const float* __restrict__ A0o,
                                                   float* __restrict__ hpart){
  __shared__ __align__(16) ushort_t Ks[64*128];
  __shared__ __align__(16) ushort_t Vt[128*64];
  __shared__ __align__(16) ushort_t Pl[4][16*64];

  const int flat = blockIdx.x;
  const int qsel = (flat >> 7) & 7;
  // qtab = {0,1,7,6,3,2,4,5}
  const int qt = (0x54236710u >> (qsel*4)) & 7;
  const int hb = flat & 127;
  const int hh = hb & 15, b = hb >> 4;

  const int tid = threadIdx.x, lane = tid & 63, w = tid >> 6, g = lane >> 4;
  const int qb0 = qt*64;
  const int row_base = b*512;
  const int qoff = hh*128;
  const int koff = 2048 + hh*128;
  const int voff = 4096 + hh*128;
  const float scale = 0.08838834764831845f;

  short8 qf[4];
  {
    int qr = qb0 + w*16 + (lane & 15);
    const ushort_t* qp = qkv + (size_t)(row_base + qr)*6144 + qoff + g*8;
    #pragma unroll
    for (int kc=0;kc<4;++kc) qf[kc] = *(const short8*)(qp + kc*32);
  }

  const int krow = tid >> 4;                 // 0..15
  const int kc_  = tid & 15;
  const int kcs  = (kc_ & 8) | ((kc_ ^ (krow & 7)) & 7);
  const int vr   = tid >> 2;                 // 0..63
  const int vd0  = (tid & 3) * 32;
  const int vrhi = vr >> 3, vrlo = vr & 7;

  const int nt = qt + 1;
  const int wmin = qb0 + w*16;

  f32x4 o[8] = {};
  float mrow[4] = {-1e30f,-1e30f,-1e30f,-1e30f};
  float lrow[4] = {0,0,0,0};

  for (int t = 0; t < nt; ++t){
    const int kv0 = t*64;
    __syncthreads();   // previous tile's reads done
    {
      const ushort_t* kg = qkv + (size_t)(row_base + kv0 + krow)*6144 + koff + kcs*8;
      #pragma unroll
      for (int i=0;i<4;++i)
        __builtin_amdgcn_global_load_lds(AS1(kg + (size_t)(i*16)*6144),
                                         AS3((char*)Ks + i*4096 + tid*16), 16, 0, 0);
    }
    {
      const ushort_t* vg = qkv + (size_t)(row_base + kv0 + vr)*6144 + voff + vd0;
      short8 vv0 = ((const short8*)vg)[0];
      short8 vv1 = ((const short8*)vg)[1];
      short8 vv2 = ((const short8*)vg)[2];
      short8 vv3 = ((const short8*)vg)[3];
      #pragma unroll
      for (int ii=0;ii<8;++ii){
        int sw = (vrhi ^ ii) << 3;
        Vt[(vd0 + ii     )*64 + sw + vrlo] = (ushort_t)vv0[ii];
        Vt[(vd0 + 8 + ii )*64 + sw + vrlo] = (ushort_t)vv1[ii];
        Vt[(vd0 + 16 + ii)*64 + sw + vrlo] = (ushort_t)vv2[ii];
        Vt[(vd0 + 24 + ii)*64 + sw + vrlo] = (ushort_t)vv3[ii];
      }
    }
    __syncthreads();   // staging visible (drains vmcnt+lgkm)

    f32x4 s4[4] = {};
    #pragma unroll
    for (int cg=0;cg<4;++cg){
      const int row = cg*16 + (lane&15);
      const int rx = row & 7;
      #pragma unroll
      for (int kc=0;kc<4;++kc){
        const int ch = kc*4 + g;
        const short8 kfv = *(const short8*)&Ks[row*128 + (((ch&8)|((ch^rx)&7))<<3)];
        s4[cg] = __builtin_amdgcn_mfma_f32_16x16x32_bf16(qf[kc], kfv, s4[cg], 0, 0, 0);
      }
    }

    const bool diag = (kv0 + 63 > wmin);
    float aa[4][4];
    float mx4[4];
    int needR = 0;
    #pragma unroll
    for (int j=0;j<4;++j){
      float a0 = s4[0][j]*scale, a1 = s4[1][j]*scale, a2 = s4[2][j]*scale, a3 = s4[3][j]*scale;
      if (diag){
        int q_abs = wmin + g*4 + j;
        int c0 = kv0 + (lane&15);
        if (c0      > q_abs) a0 = -1e30f;
        if (c0 + 16 > q_abs) a1 = -1e30f;
        if (c0 + 32 > q_abs) a2 = -1e30f;
        if (c0 + 48 > q_abs) a3 = -1e30f;
      }
      aa[j][0]=a0; aa[j][1]=a1; aa[j][2]=a2; aa[j][3]=a3;
      float mx = fmaxf(fmaxf(a0,a1), fmaxf(a2,a3));
      #pragma unroll
      for (int d=1; d<16; d<<=1) mx = fmaxf(mx, __shfl_xor(mx, d, 16));
      mx4[j] = mx;
      needR |= (mx > mrow[j] + 8.0f) ? 1 : 0;
    }
    needR = __any(needR);

    float p0[4], p1[4], p2[4], p3[4];
    if (needR){
      #pragma unroll
      for (int j=0;j<4;++j){
        float mn = fmaxf(mrow[j], mx4[j]);
        float f  = __expf(mrow[j] - mn);
        mrow[j] = mn;
        p0[j] = __expf(aa[j][0] - mn); p1[j] = __expf(aa[j][1] - mn);
        p2[j] = __expf(aa[j][2] - mn); p3[j] = __expf(aa[j][3] - mn);
        float rs = p0[j] + p1[j] + p2[j] + p3[j];
        #pragma unroll
        for (int d=1; d<16; d<<=1) rs += __shfl_xor(rs, d, 16);
        lrow[j] = lrow[j]*f + rs;
        #pragma unroll
        for (int n=0;n<8;++n) o[n][j] *= f;
      }
    } else {
      #pragma unroll
      for (int j=0;j<4;++j){
        p0[j] = __expf(aa[j][0] - mrow[j]); p1[j] = __expf(aa[j][1] - mrow[j]);
        p2[j] = __expf(aa[j][2] - mrow[j]); p3[j] = __expf(aa[j][3] - mrow[j]);
        float rs = p0[j] + p1[j] + p2[j] + p3[j];
        #pragma unroll
        for (int d=1; d<16; d<<=1) rs += __shfl_xor(rs, d, 16);
        lrow[j] += rs;
      }
    }

    {
      ushort_t* plw = &Pl[w][0];
      #pragma unroll
      for (int j=0;j<4;++j){
        const int prow = g*4 + j;
        const int rx = prow & 7;
        const int cl = (lane&15)>>3, c7 = lane&7;
        plw[prow*64 + (((0*2+cl)^rx)<<3) + c7] = f2bf(p0[j]);
        plw[prow*64 + (((1*2+cl)^rx)<<3) + c7] = f2bf(p1[j]);
        plw[prow*64 + (((2*2+cl)^rx)<<3) + c7] = f2bf(p2[j]);
        plw[prow*64 + (((3*2+cl)^rx)<<3) + c7] = f2bf(p3[j]);
      }
    }
    {
      const ushort_t* plw = &Pl[w][0];
      const int rowP = lane & 15, rxp = rowP & 7;
      const short8 pf0 = *(const short8*)&plw[rowP*64 + (((g  )^rxp)<<3)];
      const short8 pf1 = *(const short8*)&plw[rowP*64 + (((4+g)^rxp)<<3)];
      #pragma unroll
      for (int n=0;n<8;++n){
        const int d = n*16 + (lane&15);
        const int dx = d & 7;
        const short8 vf0 = *(const short8*)&Vt[d*64 + (((g  )^dx)<<3)];
        const short8 vf1 = *(const short8*)&Vt[d*64 + (((4+g)^dx)<<3)];
        o[n] = __builtin_amdgcn_mfma_f32_16x16x32_bf16(pf0, vf0, o[n], 0, 0, 0);
        o[n] = __builtin_amdgcn_mfma_f32_16x16x32_bf16(pf1, vf1, o[n], 0, 0, 0);
      }
    }
  }

  // --- epilogue: y write + h_part (fp32, deterministic: each (hh,row,r) written once)
  float invj[4];
  #pragma unroll
  for (int j=0;j<4;++j) invj[j] = 1.0f / lrow[j];

  #pragma unroll
  for (int j=0;j<4;++j){
    int qr = qb0 + w*16 + g*4 + j;
    #pragma unroll
    for (int n=0;n<8;++n)
      y[(size_t)(row_base+qr)*2048 + hh*128 + n*16 + (lane&15)] = f2bf(o[n][j]*invj[j]);
  }

  #pragma unroll
  for (int r=0;r<8;++r){
    float a0v[8];
    #pragma unroll
    for (int n=0;n<8;++n)
      a0v[n] = A0o[(size_t)r*2048 + hh*128 + n*16 + (lane&15)];
    #pragma unroll
    for (int j=0;j<4;++j){
      float s = 0.f;
      #pragma unroll
      for (int n=0;n<8;++n) s += o[n][j]*a0v[n];
      s *= invj[j];
      #pragma unroll
      for (int d=1; d<16; d<<=1) s += __shfl_xor(s, d, 16);
      if ((lane & 15) == 0){
        int qr = qb0 + w*16 + g*4 + j;
        hpart[((size_t)hh*4096 + row_base + qr)*8 + r] = s;
      }
    }
  }
}

// ---------------------------------------------------------------- launch
extern "C" void kernel_launch(void* const* d_in, const int* in_sizes, int n_in,
                              void* d_out, int out_size, void* d_ws, size_t ws_size,
                              hipStream_t stream){
  const float* x       = (const float*)d_in[0];
  const float* Wqkv    = (const float*)d_in[1];
  const float* A0_qkv  = (const float*)d_in[2];
  const float* B0_qkv  = (const float*)d_in[3];
  const float* da_qkv  = (const float*)d_in[4];
  const float* db_qkv  = (const float*)d_in[5];
  const float* Wout    = (const float*)d_in[6];
  const float* A0_out  = (const float*)d_in[7];
  const float* B0_out  = (const float*)d_in[8];
  const float* da_out  = (const float*)d_in[9];
  const float* db_out  = (const float*)d_in[10];
  const float* cosb    = (const float*)d_in[11];
  const float* sinb    = (const float*)d_in[12];
  float* out = (float*)d_out;

  char* ws = (char*)d_ws;
  ushort_t* x_bf    = (ushort_t*)(ws);
  ushort_t* wqkv_bf = (ushort_t*)(ws + 16777216);
  ushort_t* wout_bf = (ushort_t*)(ws + 41943040);
  ushort_t* qkv_bf  = (ushort_t*)(ws + 50331648);
  ushort_t* y_bf    = (ushort_t*)(ws + 100663296);
  float*    h_qkv   = (float*)   (ws + 117440512);
  float*    h_out   = (float*)   (ws + 117571584);
  float*    h_part  = (float*)   (ws + 117702656);   // [16][4096][8] f32 = 2 MB

  const int M = 4096;
  const int C = 2048;
  const int N3 = 6144;

  conv_f2b<<<12288,256, 0, stream>>>(Wqkv, wqkv_bf, N3*C);
  conv_f2b<<<4096, 256, 0, stream>>>(Wout, wout_bf, C*C);

  lora_h_f32<<<M, 256, 0, stream>>>(x, x_bf, A0_qkv, da_qkv, db_qkv, h_qkv, C);

  gemm256x192_lora<<<(M/256)*(N3/192), 512, 0, stream>>>(x_bf, wqkv_bf, h_qkv, B0_qkv,
                                                         qkv_bf, M, N3, C);

  rope_kernel<<<4096, 256, 0, stream>>>(qkv_bf, cosb, sinb);

  attn_kernel<<<1024, 256, 0, stream>>>(qkv_bf, y_bf, A0_out, h_part);

  lora_reduce<<<128, 256, 0, stream>>>(h_part, da_out, db_out, h_out);

  gemm128x256_lora<1><<<(M/128)*(C/256), 512, 0, stream>>>(y_bf, wout_bf, h_out, B0_out,
                                                           out, M, C, C);
}

// Round 24
// 226.873 us; speedup vs baseline: 1.0417x; 1.0417x over previous
//
#include <hip/hip_runtime.h>

typedef unsigned short ushort_t;
typedef __attribute__((ext_vector_type(8))) short short8;
typedef __attribute__((ext_vector_type(4))) float f32x4;

#define AS1(p) ((const __attribute__((address_space(1))) void*)(p))
#define AS3(p) ((__attribute__((address_space(3))) void*)(p))

__device__ __forceinline__ ushort_t f2bf(float f){
  unsigned u = __float_as_uint(f);
  u += 0x7FFFu + ((u>>16)&1u);
  return (ushort_t)(u>>16);
}
__device__ __forceinline__ float bf2f(ushort_t h){
  return __uint_as_float(((unsigned)h)<<16);
}

// ---------------------------------------------------------------- conv fp32->bf16
__global__ __launch_bounds__(256) void conv_f2b(const float* __restrict__ src,
                                                ushort_t* __restrict__ dst, int n){
  int i = (blockIdx.x*256 + threadIdx.x)*4;
  if (i < n){
    float4 v = *(const float4*)&src[i];
    ushort_t o0=f2bf(v.x), o1=f2bf(v.y), o2=f2bf(v.z), o3=f2bf(v.w);
    ushort4 o; o.x=o0; o.y=o1; o.z=o2; o.w=o3;
    *(ushort4*)&dst[i] = o;
  }
}

// ---------------------------------------------------------------- LoRA h = X @ A0^T * (da*db)  (f32 input, fused bf16 conv)
__global__ __launch_bounds__(256) void lora_h_f32(const float* __restrict__ X,
                                                  ushort_t* __restrict__ Xbf,
                                                  const float* __restrict__ A0,
                                                  const float* __restrict__ da,
                                                  const float* __restrict__ db,
                                                  float* __restrict__ out, int K){
  int m = blockIdx.x;
  int tid = threadIdx.x, lane = tid & 63, w = tid >> 6;
  float part[8] = {0,0,0,0,0,0,0,0};
  for (int k = tid; k < K; k += 256){
    float xv = X[(size_t)m*K + k];
    Xbf[(size_t)m*K + k] = f2bf(xv);
    #pragma unroll
    for (int r=0;r<8;++r) part[r] += xv * A0[r*K + k];
  }
  #pragma unroll
  for (int r=0;r<8;++r)
    for (int d=1;d<64;d<<=1) part[r] += __shfl_xor(part[r], d, 64);
  __shared__ float wsum[4][8];
  if (lane==0){
    #pragma unroll
    for (int r=0;r<8;++r) wsum[w][r] = part[r];
  }
  __syncthreads();
  if (tid < 8){
    float s = wsum[0][tid]+wsum[1][tid]+wsum[2][tid]+wsum[3][tid];
    out[(size_t)m*8 + tid] = s * da[tid]*db[tid];
  }
}

// ---------------------------------------------------------------- reduce h_part over heads
__global__ __launch_bounds__(256) void lora_reduce(const float* __restrict__ hpart,
                                                   const float* __restrict__ da,
                                                   const float* __restrict__ db,
                                                   float* __restrict__ out){
  int i = blockIdx.x*256 + threadIdx.x;   // 0..32767 (4096 rows x 8 ranks)
  int r = i & 7;
  float s = 0.f;
  #pragma unroll
  for (int hh=0; hh<16; ++hh) s += hpart[(size_t)hh*32768 + i];
  out[i] = s * da[r]*db[r];
}

// ---------------------------------------------------------------- 256x192 3-phase GEMM + LoRA (bf16 out, QKV)
__global__ __launch_bounds__(512, 1) void gemm256x192_lora(
    const ushort_t* __restrict__ A, const ushort_t* __restrict__ Bw,
    const float* __restrict__ hmat, const float* __restrict__ B0,
    ushort_t* __restrict__ C, int M, int N, int K)
{
  __shared__ __align__(16) char smem[114688];
  const int tid = threadIdx.x, lane = tid & 63, w = tid >> 6;
  const int wm = w >> 1, wn = w & 1;

  const int nbn = N / 192;
  const int nwg = (M >> 8) * nbn;
  const int q8 = nwg >> 3;
  const int swz = ((int)blockIdx.x & 7)*q8 + ((int)blockIdx.x >> 3);
  const int m0 = (swz / nbn) << 8, n0 = (swz % nbn) * 192;

  const int NTt = K >> 6;
  const int srow8  = tid >> 3;
  const int schunk = (lane & 7) ^ (lane >> 3);

  #define STAGE_AU(u, tt, bb) do { \
    const ushort_t* g_ = A + (size_t)(m0 + (u)*64 + srow8)*K + (tt)*64 + schunk*8; \
    __builtin_amdgcn_global_load_lds(AS1(g_), AS3(smem + (bb)*32768 + (u)*8192 + tid*16), 16, 0, 0); \
  } while(0)
  #define STAGE_BU(u, tt, bb) do { \
    const ushort_t* g_ = Bw + (size_t)(n0 + (u)*64 + srow8)*K + (tt)*64 + schunk*8; \
    __builtin_amdgcn_global_load_lds(AS1(g_), AS3(smem + 65536 + (bb)*24576 + (u)*8192 + tid*16), 16, 0, 0); \
  } while(0)

  #define RDA(bb, q, kk) (*(const short8*)(smem + (bb)*32768 + \
      ((q)*64 + wm*16 + (lane&15))*128 + ((((kk)*4 + (lane>>4)) ^ (lane&7))<<4)))
  #define RDB(bb, r, kk) (*(const short8*)(smem + 65536 + (bb)*24576 + \
      ((r)*32 + wn*16 + (lane&15))*128 + ((((kk)*4 + (lane>>4)) ^ (lane&7))<<4)))

  #define MM(q, r, bi) do{ \
    acc[q][r] = __builtin_amdgcn_mfma_f32_16x16x32_bf16(aF[q][0], bF[bi][0], acc[q][r], 0,0,0); \
    acc[q][r] = __builtin_amdgcn_mfma_f32_16x16x32_bf16(aF[q][1], bF[bi][1], acc[q][r], 0,0,0); \
  }while(0)

  #define BARRIER() asm volatile("s_barrier" ::: "memory")

  short8 aF[4][2];
  short8 bF[2][2];
  f32x4 acc[4][6] = {};

  STAGE_AU(0,0,0); STAGE_AU(1,0,0); STAGE_AU(2,0,0); STAGE_AU(3,0,0);
  STAGE_BU(0,0,0); STAGE_BU(1,0,0); STAGE_BU(2,0,0);
  asm volatile("s_waitcnt vmcnt(2)" ::: "memory");
  BARRIER();

  for (int t = 0; t < NTt-1; ++t){
    const int b = t & 1, nb = b ^ 1;
    #pragma unroll
    for (int q=0;q<4;++q){ aF[q][0]=RDA(b,q,0); aF[q][1]=RDA(b,q,1); }
    #pragma unroll
    for (int rl=0;rl<2;++rl){ bF[rl][0]=RDB(b,rl,0); bF[rl][1]=RDB(b,rl,1); }
    STAGE_AU(0,t+1,nb); STAGE_AU(1,t+1,nb);
    __builtin_amdgcn_s_setprio(1);
    MM(0,0,0); MM(0,1,1); MM(1,0,0); MM(1,1,1);
    MM(2,0,0); MM(2,1,1); MM(3,0,0); MM(3,1,1);
    __builtin_amdgcn_s_setprio(0);
    asm volatile("s_waitcnt vmcnt(3)" ::: "memory");
    BARRIER();
    #pragma unroll
    for (int rl=0;rl<2;++rl){ bF[rl][0]=RDB(b,rl+2,0); bF[rl][1]=RDB(b,rl+2,1); }
    STAGE_AU(2,t+1,nb); STAGE_AU(3,t+1,nb); STAGE_BU(0,t+1,nb);
    __builtin_amdgcn_s_setprio(1);
    MM(0,2,0); MM(0,3,1); MM(1,2,0); MM(1,3,1);
    MM(2,2,0); MM(2,3,1); MM(3,2,0); MM(3,3,1);
    __builtin_amdgcn_s_setprio(0);
    asm volatile("s_waitcnt vmcnt(5)" ::: "memory");
    BARRIER();
    #pragma unroll
    for (int rl=0;rl<2;++rl){ bF[rl][0]=RDB(b,rl+4,0); bF[rl][1]=RDB(b,rl+4,1); }
    STAGE_BU(1,t+1,nb); STAGE_BU(2,t+1,nb);
    __builtin_amdgcn_s_setprio(1);
    MM(0,4,0); MM(0,5,1); MM(1,4,0); MM(1,5,1);
    MM(2,4,0); MM(2,5,1); MM(3,4,0); MM(3,5,1);
    __builtin_amdgcn_s_setprio(0);
    asm volatile("s_waitcnt lgkmcnt(0)" ::: "memory");
    asm volatile("s_waitcnt vmcnt(2)" ::: "memory");
    BARRIER();
  }

  {
    const int b = (NTt-1) & 1;
    #pragma unroll
    for (int q=0;q<4;++q){ aF[q][0]=RDA(b,q,0); aF[q][1]=RDA(b,q,1); }
    #pragma unroll
    for (int rl=0;rl<2;++rl){ bF[rl][0]=RDB(b,rl,0); bF[rl][1]=RDB(b,rl,1); }
    __builtin_amdgcn_s_setprio(1);
    MM(0,0,0); MM(0,1,1); MM(1,0,0); MM(1,1,1);
    MM(2,0,0); MM(2,1,1); MM(3,0,0); MM(3,1,1);
    __builtin_amdgcn_s_setprio(0);
    asm volatile("s_waitcnt vmcnt(1)" ::: "memory");
    BARRIER();
    #pragma unroll
    for (int rl=0;rl<2;++rl){ bF[rl][0]=RDB(b,rl+2,0); bF[rl][1]=RDB(b,rl+2,1); }
    __builtin_amdgcn_s_setprio(1);
    MM(0,2,0); MM(0,3,1); MM(1,2,0); MM(1,3,1);
    MM(2,2,0); MM(2,3,1); MM(3,2,0); MM(3,3,1);
    __builtin_amdgcn_s_setprio(0);
    asm volatile("s_waitcnt vmcnt(0)" ::: "memory");
    BARRIER();
    #pragma unroll
    for (int rl=0;rl<2;++rl){ bF[rl][0]=RDB(b,rl+4,0); bF[rl][1]=RDB(b,rl+4,1); }
    MM(0,4,0); MM(0,5,1); MM(1,4,0); MM(1,5,1);
    MM(2,4,0); MM(2,5,1); MM(3,4,0); MM(3,5,1);
  }

  float b0v[6][8];
  #pragma unroll
  for (int r=0;r<6;++r){
    int col = n0 + r*32 + wn*16 + (lane&15);
    const float4* bp = (const float4*)&B0[(size_t)col*8];
    float4 u0 = bp[0], u1 = bp[1];
    b0v[r][0]=u0.x; b0v[r][1]=u0.y; b0v[r][2]=u0.z; b0v[r][3]=u0.w;
    b0v[r][4]=u1.x; b0v[r][5]=u1.y; b0v[r][6]=u1.z; b0v[r][7]=u1.w;
  }
  #pragma unroll
  for (int q=0;q<4;++q){
    #pragma unroll
    for (int jj=0;jj<4;++jj){
      int row = m0 + q*64 + wm*16 + (lane>>4)*4 + jj;
      const float4* hp = (const float4*)&hmat[(size_t)row*8];
      float4 h0 = hp[0], h1 = hp[1];
      #pragma unroll
      for (int r=0;r<6;++r){
        float lor = h0.x*b0v[r][0]+h0.y*b0v[r][1]+h0.z*b0v[r][2]+h0.w*b0v[r][3]
                  + h1.x*b0v[r][4]+h1.y*b0v[r][5]+h1.z*b0v[r][6]+h1.w*b0v[r][7];
        int col = n0 + r*32 + wn*16 + (lane&15);
        C[(size_t)row*N + col] = f2bf(acc[q][r][jj] + 0.125f*lor);
      }
    }
  }
  #undef STAGE_AU
  #undef STAGE_BU
  #undef RDA
  #undef RDB
  #undef MM
  #undef BARRIER
}

// ---------------------------------------------------------------- 128x256 2-phase GEMM + LoRA (out-proj)
template<int MODE>
__global__ __launch_bounds__(512, 1) void gemm128x256_lora(
    const ushort_t* __restrict__ A, const ushort_t* __restrict__ Bw,
    const float* __restrict__ hmat, const float* __restrict__ B0,
    void* __restrict__ C, int M, int N, int K)
{
  __shared__ __align__(16) char smem[98304];
  const int tid = threadIdx.x, lane = tid & 63, w = tid >> 6;
  const int wm = w >> 2, wn = w & 3;

  const int nbn = N >> 8;
  const int nwg = (M >> 7) * nbn;
  const int q8 = nwg >> 3;
  const int swz = ((int)blockIdx.x & 7)*q8 + ((int)blockIdx.x >> 3);
  const int m0 = (swz / nbn) << 7, n0 = (swz % nbn) << 8;

  const int NTt = K >> 6;

  const int srow8  = tid >> 3;
  const int schunk = (lane & 7) ^ (lane >> 3);

  #define STAGE_AU(u, tt, bb) do { \
    const ushort_t* g_ = A + (size_t)(m0 + (u)*64 + srow8)*K + (tt)*64 + schunk*8; \
    __builtin_amdgcn_global_load_lds(AS1(g_), AS3(smem + (bb)*16384 + (u)*8192 + w*1024), 16, 0, 0); \
  } while(0)
  #define STAGE_BU(u, tt, bb) do { \
    const ushort_t* g_ = Bw + (size_t)(n0 + (u)*64 + srow8)*K + (tt)*64 + schunk*8; \
    __builtin_amdgcn_global_load_lds(AS1(g_), AS3(smem + 32768 + (bb)*32768 + (u)*8192 + w*1024), 16, 0, 0); \
  } while(0)

  #define RDA(bb, q, kk) (*(const short8*)(smem + (bb)*16384 + \
      ((q)*32 + wm*16 + (lane&15))*128 + ((((kk)*4 + (lane>>4)) ^ (lane&7))<<4)))
  #define RDB(bb, rg, kk) (*(const short8*)(smem + 32768 + (bb)*32768 + \
      ((rg)*64 + wn*16 + (lane&15))*128 + ((((kk)*4 + (lane>>4)) ^ (lane&7))<<4)))

  #define MM0(q,rl) do{ \
    acc[q][rl] = __builtin_amdgcn_mfma_f32_16x16x32_bf16(aF[q][0], bF[rl][0], acc[q][rl], 0,0,0); \
    acc[q][rl] = __builtin_amdgcn_mfma_f32_16x16x32_bf16(aF[q][1], bF[rl][1], acc[q][rl], 0,0,0); \
  }while(0)
  #define MM1(q,rl) do{ \
    acc[q][(rl)+2] = __builtin_amdgcn_mfma_f32_16x16x32_bf16(aF[q][0], bF[rl][0], acc[q][(rl)+2], 0,0,0); \
    acc[q][(rl)+2] = __builtin_amdgcn_mfma_f32_16x16x32_bf16(aF[q][1], bF[rl][1], acc[q][(rl)+2], 0,0,0); \
  }while(0)

  #define BARRIER() asm volatile("s_barrier" ::: "memory")

  short8 aF[4][2];
  short8 bF[2][2];
  f32x4 acc[4][4] = {};

  STAGE_AU(0,0,0); STAGE_AU(1,0,0); STAGE_BU(0,0,0); STAGE_BU(1,0,0);
  STAGE_BU(2,0,0); STAGE_BU(3,0,0);
  asm volatile("s_waitcnt vmcnt(2)" ::: "memory");
  BARRIER();

  for (int t = 0; t < NTt-1; ++t){
    const int b = t & 1, nb = b ^ 1;
    #pragma unroll
    for (int q=0;q<4;++q){ aF[q][0]=RDA(b,q,0); aF[q][1]=RDA(b,q,1); }
    #pragma unroll
    for (int rl=0;rl<2;++rl){ bF[rl][0]=RDB(b,rl,0); bF[rl][1]=RDB(b,rl,1); }
    STAGE_AU(0,t+1,nb); STAGE_AU(1,t+1,nb); STAGE_BU(0,t+1,nb); STAGE_BU(1,t+1,nb);
    __builtin_amdgcn_s_setprio(1);
    MM0(0,0); MM0(0,1); MM0(1,0); MM0(1,1);
    MM0(2,0); MM0(2,1); MM0(3,0); MM0(3,1);
    __builtin_amdgcn_s_setprio(0);
    asm volatile("s_waitcnt vmcnt(4)" ::: "memory");
    BARRIER();
    #pragma unroll
    for (int rl=0;rl<2;++rl){ bF[rl][0]=RDB(b,rl+2,0); bF[rl][1]=RDB(b,rl+2,1); }
    STAGE_BU(2,t+1,nb); STAGE_BU(3,t+1,nb);
    __builtin_amdgcn_s_setprio(1);
    MM1(0,0); MM1(0,1); MM1(1,0); MM1(1,1);
    MM1(2,0); MM1(2,1); MM1(3,0); MM1(3,1);
    __builtin_amdgcn_s_setprio(0);
    asm volatile("s_waitcnt lgkmcnt(0)" ::: "memory");
    asm volatile("s_waitcnt vmcnt(2)" ::: "memory");
    BARRIER();
  }

  {
    const int b = (NTt-1) & 1;
    #pragma unroll
    for (int q=0;q<4;++q){ aF[q][0]=RDA(b,q,0); aF[q][1]=RDA(b,q,1); }
    #pragma unroll
    for (int rl=0;rl<2;++rl){ bF[rl][0]=RDB(b,rl,0); bF[rl][1]=RDB(b,rl,1); }
    __builtin_amdgcn_s_setprio(1);
    MM0(0,0); MM0(0,1); MM0(1,0); MM0(1,1);
    MM0(2,0); MM0(2,1); MM0(3,0); MM0(3,1);
    __builtin_amdgcn_s_setprio(0);
    asm volatile("s_waitcnt vmcnt(0)" ::: "memory");
    BARRIER();
    #pragma unroll
    for (int rl=0;rl<2;++rl){ bF[rl][0]=RDB(b,rl+2,0); bF[rl][1]=RDB(b,rl+2,1); }
    MM1(0,0); MM1(0,1); MM1(1,0); MM1(1,1);
    MM1(2,0); MM1(2,1); MM1(3,0); MM1(3,1);
  }

  float b0v[4][8];
  #pragma unroll
  for (int r=0;r<4;++r){
    int col = n0 + r*64 + wn*16 + (lane&15);
    const float4* bp = (const float4*)&B0[(size_t)col*8];
    float4 u0 = bp[0], u1 = bp[1];
    b0v[r][0]=u0.x; b0v[r][1]=u0.y; b0v[r][2]=u0.z; b0v[r][3]=u0.w;
    b0v[r][4]=u1.x; b0v[r][5]=u1.y; b0v[r][6]=u1.z; b0v[r][7]=u1.w;
  }
  #pragma unroll
  for (int q=0;q<4;++q){
    #pragma unroll
    for (int jj=0;jj<4;++jj){
      int row = m0 + q*32 + wm*16 + (lane>>4)*4 + jj;
      const float4* hp = (const float4*)&hmat[(size_t)row*8];
      float4 h0 = hp[0], h1 = hp[1];
      #pragma unroll
      for (int r=0;r<4;++r){
        float lor = h0.x*b0v[r][0]+h0.y*b0v[r][1]+h0.z*b0v[r][2]+h0.w*b0v[r][3]
                  + h1.x*b0v[r][4]+h1.y*b0v[r][5]+h1.z*b0v[r][6]+h1.w*b0v[r][7];
        int col = n0 + r*64 + wn*16 + (lane&15);
        float v = acc[q][r][jj] + 0.125f*lor;
        if (MODE==0) ((ushort_t*)C)[(size_t)row*N + col] = f2bf(v);
        else         ((float*)C)[(size_t)row*N + col]    = v;
      }
    }
  }
  #undef STAGE_AU
  #undef STAGE_BU
  #undef RDA
  #undef RDB
  #undef MM0
  #undef MM1
  #undef BARRIER
}

// ---------------------------------------------------------------- RoPE (in place on qkv bf16)
__global__ __launch_bounds__(256) void rope_kernel(ushort_t* __restrict__ qkv,
                                                   const float* __restrict__ cosb,
                                                   const float* __restrict__ sinb){
  int idx = blockIdx.x*256 + threadIdx.x;
  int d = idx & 7;
  int g = idx >> 3;
  int h_ = g & 15;
  int s  = (g>>4) & 1;
  int t  = (g>>5) & 511;
  int b  = g >> 14;
  size_t base = (size_t)(b*512 + t)*6144 + s*2048 + h_*128;
  float x1 = bf2f(qkv[base+d]), x2 = bf2f(qkv[base+d+8]);
  float c = cosb[t*8+d], sn = sinb[t*8+d];
  qkv[base+d]   = f2bf(x1*c - x2*sn);
  qkv[base+d+8] = f2bf(x2*c + x1*sn);
}

// ---------------------------------------------------------------- flash attention (+ fused h_out partials)
// QBLK=128 (8 waves x 16 rows), KVBLK=64, double-buffered K/V, async staging.
// Gray-code qt remap balances causal load; T13 defer-max.
// Epilogue: writes y (bf16) AND h_part[hh][row][8].
__global__ __launch_bounds__(512) void attn_kernel(const ushort_t* __restrict__ qkv,
                                                   ushort_t* __restrict__ y,
                                                   const float* __restrict__ A0o,
                                                   float* __restrict__ hpart){
  __shared__ __align__(16) ushort_t Ks[2][64*128];
  __shared__ __align__(16) ushort_t Vt[2][128*64];
  __shared__ __align__(16) ushort_t Pl[8][16*64];

  const int flat = blockIdx.x;
  const int qt = ((flat >> 7) ^ ((flat >> 8) & 1)) & 3;
  const int hb = flat & 127;
  const int hh = hb & 15, b = hb >> 4;

  const int tid = threadIdx.x, lane = tid & 63, w = tid >> 6, g = lane >> 4;
  const int qb0 = qt*128;
  const int row_base = b*512;
  const int qoff = hh*128;
  const int koff = 2048 + hh*128;
  const int voff = 4096 + hh*128;
  const float scale = 0.08838834764831845f;

  short8 qf[4];
  {
    int qr = qb0 + w*16 + (lane & 15);
    const ushort_t* qp = qkv + (size_t)(row_base + qr)*6144 + qoff + g*8;
    #pragma unroll
    for (int kc=0;kc<4;++kc) qf[kc] = *(const short8*)(qp + kc*32);
  }

  const int krow = tid >> 4;
  const int kc_  = tid & 15;
  const int kcs  = (kc_ & 8) | ((kc_ ^ (krow & 7)) & 7);
  const int vr   = tid >> 3;
  const int vd0  = (tid & 7) * 16;
  const int vrhi = vr >> 3, vrlo = vr & 7;

  const int nt = 2*qt + 2;
  const int wmin = qb0 + w*16;
  const int wmax = wmin + 15;

  f32x4 o[8] = {};
  float mrow[4] = {-1e30f,-1e30f,-1e30f,-1e30f};
  float lrow[4] = {0,0,0,0};

  short8 vv0, vv1;

  {
    const ushort_t* kg = qkv + (size_t)(row_base + krow)*6144 + koff + kcs*8;
    __builtin_amdgcn_global_load_lds(AS1(kg), AS3((char*)&Ks[0][0] + tid*16), 16, 0, 0);
    __builtin_amdgcn_global_load_lds(AS1(kg + (size_t)32*6144), AS3((char*)&Ks[0][0] + 8192 + tid*16), 16, 0, 0);
    const ushort_t* vg = qkv + (size_t)(row_base + vr)*6144 + voff + vd0;
    vv0 = ((const short8*)vg)[0];
    vv1 = ((const short8*)vg)[1];
    #pragma unroll
    for (int ii=0;ii<8;++ii){
      int sw = (vrhi ^ ii) << 3;
      Vt[0][(vd0 + ii    )*64 + sw + vrlo] = (ushort_t)vv0[ii];
      Vt[0][(vd0 + 8 + ii)*64 + sw + vrlo] = (ushort_t)vv1[ii];
    }
  }
  __syncthreads();

  for (int t = 0; t < nt; ++t){
    const int bb = t & 1, nb = bb ^ 1;
    const int kv0 = t*64;
    const bool have_next = (t+1 < nt);

    if (have_next){
      const int kv1 = kv0 + 64;
      const ushort_t* kg = qkv + (size_t)(row_base + kv1 + krow)*6144 + koff + kcs*8;
      __builtin_amdgcn_global_load_lds(AS1(kg), AS3((char*)&Ks[nb][0] + tid*16), 16, 0, 0);
      __builtin_amdgcn_global_load_lds(AS1(kg + (size_t)32*6144), AS3((char*)&Ks[nb][0] + 8192 + tid*16), 16, 0, 0);
      const ushort_t* vg = qkv + (size_t)(row_base + kv1 + vr)*6144 + voff + vd0;
      vv0 = ((const short8*)vg)[0];
      vv1 = ((const short8*)vg)[1];
    }

    if (kv0 <= wmax){
      f32x4 s4[4] = {};
      #pragma unroll
      for (int cg=0;cg<4;++cg){
        const int row = cg*16 + (lane&15);
        const int rx = row & 7;
        #pragma unroll
        for (int kc=0;kc<4;++kc){
          const int ch = kc*4 + g;
          const short8 kfv = *(const short8*)&Ks[bb][row*128 + (((ch&8)|((ch^rx)&7))<<3)];
          s4[cg] = __builtin_amdgcn_mfma_f32_16x16x32_bf16(qf[kc], kfv, s4[cg], 0, 0, 0);
        }
      }

      const bool diag = (kv0 + 63 > wmin);
      float aa[4][4];
      float mx4[4];
      int needR = 0;
      #pragma unroll
      for (int j=0;j<4;++j){
        float a0 = s4[0][j]*scale, a1 = s4[1][j]*scale, a2 = s4[2][j]*scale, a3 = s4[3][j]*scale;
        if (diag){
          int q_abs = wmin + g*4 + j;
          int c0 = kv0 + (lane&15);
          if (c0      > q_abs) a0 = -1e30f;
          if (c0 + 16 > q_abs) a1 = -1e30f;
          if (c0 + 32 > q_abs) a2 = -1e30f;
          if (c0 + 48 > q_abs) a3 = -1e30f;
        }
        aa[j][0]=a0; aa[j][1]=a1; aa[j][2]=a2; aa[j][3]=a3;
        float mx = fmaxf(fmaxf(a0,a1), fmaxf(a2,a3));
        #pragma unroll
        for (int d=1; d<16; d<<=1) mx = fmaxf(mx, __shfl_xor(mx, d, 16));
        mx4[j] = mx;
        needR |= (mx > mrow[j] + 8.0f) ? 1 : 0;
      }
      needR = __any(needR);

      float p0[4], p1[4], p2[4], p3[4];
      if (needR){
        #pragma unroll
        for (int j=0;j<4;++j){
          float mn = fmaxf(mrow[j], mx4[j]);
          float f  = __expf(mrow[j] - mn);
          mrow[j] = mn;
          p0[j] = __expf(aa[j][0] - mn); p1[j] = __expf(aa[j][1] - mn);
          p2[j] = __expf(aa[j][2] - mn); p3[j] = __expf(aa[j][3] - mn);
          float rs = p0[j] + p1[j] + p2[j] + p3[j];
          #pragma unroll
          for (int d=1; d<16; d<<=1) rs += __shfl_xor(rs, d, 16);
          lrow[j] = lrow[j]*f + rs;
          #pragma unroll
          for (int n=0;n<8;++n) o[n][j] *= f;
        }
      } else {
        #pragma unroll
        for (int j=0;j<4;++j){
          p0[j] = __expf(aa[j][0] - mrow[j]); p1[j] = __expf(aa[j][1] - mrow[j]);
          p2[j] = __expf(aa[j][2] - mrow[j]); p3[j] = __expf(aa[j][3] - mrow[j]);
          float rs = p0[j] + p1[j] + p2[j] + p3[j];
          #pragma unroll
          for (int d=1; d<16; d<<=1) rs += __shfl_xor(rs, d, 16);
          lrow[j] += rs;
        }
      }

      {
        ushort_t* plw = &Pl[w][0];
        #pragma unroll
        for (int j=0;j<4;++j){
          const int prow = g*4 + j;
          const int rx = prow & 7;
          const int cl = (lane&15)>>3, c7 = lane&7;
          plw[prow*64 + (((0*2+cl)^rx)<<3) + c7] = f2bf(p0[j]);
          plw[prow*64 + (((1*2+cl)^rx)<<3) + c7] = f2bf(p1[j]);
          plw[prow*64 + (((2*2+cl)^rx)<<3) + c7] = f2bf(p2[j]);
          plw[prow*64 + (((3*2+cl)^rx)<<3) + c7] = f2bf(p3[j]);
        }
      }
      {
        const ushort_t* plw = &Pl[w][0];
        const int rowP = lane & 15, rxp = rowP & 7;
        const short8 pf0 = *(const short8*)&plw[rowP*64 + (((g  )^rxp)<<3)];
        const short8 pf1 = *(const short8*)&plw[rowP*64 + (((4+g)^rxp)<<3)];
        #pragma unroll
        for (int n=0;n<8;++n){
          const int d = n*16 + (lane&15);
          const int dx = d & 7;
          const short8 vf0 = *(const short8*)&Vt[bb][d*64 + (((g  )^dx)<<3)];
          const short8 vf1 = *(const short8*)&Vt[bb][d*64 + (((4+g)^dx)<<3)];
          o[n] = __builtin_amdgcn_mfma_f32_16x16x32_bf16(pf0, vf0, o[n], 0, 0, 0);
          o[n] = __builtin_amdgcn_mfma_f32_16x16x32_bf16(pf1, vf1, o[n], 0, 0, 0);
        }
      }
    }

    if (have_next){
      #pragma unroll
      for (int ii=0;ii<8;++ii){
        int sw = (vrhi ^ ii) << 3;
        Vt[nb][(vd0 + ii    )*64 + sw + vrlo] = (ushort_t)vv0[ii];
        Vt[nb][(vd0 + 8 + ii)*64 + sw + vrlo] = (ushort_t)vv1[ii];
      }
    }
    __syncthreads();
  }

  // --- epilogue: y write + h_part (fp32, deterministic: each (hh,row,r) written once)
  float invj[4];
  #pragma unroll
  for (int j=0;j<4;++j) invj[j] = 1.0f / lrow[j];

  #pragma unroll
  for (int j=0;j<4;++j){
    int qr = qb0 + w*16 + g*4 + j;
    #pragma unroll
    for (int n=0;n<8;++n)
      y[(size_t)(row_base+qr)*2048 + hh*128 + n*16 + (lane&15)] = f2bf(o[n][j]*invj[j]);
  }

  #pragma unroll
  for (int r=0;r<8;++r){
    float a0v[8];
    #pragma unroll
    for (int n=0;n<8;++n)
      a0v[n] = A0o[(size_t)r*2048 + hh*128 + n*16 + (lane&15)];
    #pragma unroll
    for (int j=0;j<4;++j){
      float s = 0.f;
      #pragma unroll
      for (int n=0;n<8;++n) s += o[n][j]*a0v[n];
      s *= invj[j];
      #pragma unroll
      for (int d=1; d<16; d<<=1) s += __shfl_xor(s, d, 16);
      if ((lane & 15) == 0){
        int qr = qb0 + w*16 + g*4 + j;
        hpart[((size_t)hh*4096 + row_base + qr)*8 + r] = s;
      }
    }
  }
}

// ---------------------------------------------------------------- launch
extern "C" void kernel_launch(void* const* d_in, const int* in_sizes, int n_in,
                              void* d_out, int out_size, void* d_ws, size_t ws_size,
                              hipStream_t stream){
  const float* x       = (const float*)d_in[0];
  const float* Wqkv    = (const float*)d_in[1];
  const float* A0_qkv  = (const float*)d_in[2];
  const float* B0_qkv  = (const float*)d_in[3];
  const float* da_qkv  = (const float*)d_in[4];
  const float* db_qkv  = (const float*)d_in[5];
  const float* Wout    = (const float*)d_in[6];
  const float* A0_out  = (const float*)d_in[7];
  const float* B0_out  = (const float*)d_in[8];
  const float* da_out  = (const float*)d_in[9];
  const float* db_out  = (const float*)d_in[10];
  const float* cosb    = (const float*)d_in[11];
  const float* sinb    = (const float*)d_in[12];
  float* out = (float*)d_out;

  char* ws = (char*)d_ws;
  ushort_t* x_bf    = (ushort_t*)(ws);
  ushort_t* wqkv_bf = (ushort_t*)(ws + 16777216);
  ushort_t* wout_bf = (ushort_t*)(ws + 41943040);
  ushort_t* qkv_bf  = (ushort_t*)(ws + 50331648);
  ushort_t* y_bf    = (ushort_t*)(ws + 100663296);
  float*    h_qkv   = (float*)   (ws + 117440512);
  float*    h_out   = (float*)   (ws + 117571584);
  float*    h_part  = (float*)   (ws + 117702656);   // [16][4096][8] f32 = 2 MB

  const int M = 4096;
  const int C = 2048;
  const int N3 = 6144;

  conv_f2b<<<12288,256, 0, stream>>>(Wqkv, wqkv_bf, N3*C);
  conv_f2b<<<4096, 256, 0, stream>>>(Wout, wout_bf, C*C);

  lora_h_f32<<<M, 256, 0, stream>>>(x, x_bf, A0_qkv, da_qkv, db_qkv, h_qkv, C);

  gemm256x192_lora<<<(M/256)*(N3/192), 512, 0, stream>>>(x_bf, wqkv_bf, h_qkv, B0_qkv,
                                                         qkv_bf, M, N3, C);

  rope_kernel<<<4096, 256, 0, stream>>>(qkv_bf, cosb, sinb);

  attn_kernel<<<512, 512, 0, stream>>>(qkv_bf, y_bf, A0_out, h_part);

  lora_reduce<<<128, 256, 0, stream>>>(h_part, da_out, db_out, h_out);

  gemm128x256_lora<1><<<(M/128)*(C/256), 512, 0, stream>>>(y_bf, wout_bf, h_out, B0_out,
                                                           out, M, C, C);
}